// Round 3
// baseline (208.641 us; speedup 1.0000x reference)
//
#include <hip/hip_runtime.h>

#define NL 30

typedef float f32x2 __attribute__((ext_vector_type(2)));

// Pre-kernel: duplicate each scalar param into both lanes of an f32x2 so the
// main kernel can s_load a ready-made 64-bit packed operand for v_pk_fma_f32
// (no per-layer v_mov splat pairs). Layout per layer l (11 f32x2 slots):
//   [0..4] = w1 dup, [5] = bias dup, [6..10] = w2 dup.
__global__ void pack_params(const float* __restrict__ W1,
                            const float* __restrict__ b1,
                            const float* __restrict__ W2,
                            f32x2* __restrict__ pw) {
    int i = blockIdx.x * blockDim.x + threadIdx.x;
    if (i >= NL * 11) return;
    int l = i / 11, k = i % 11;
    float v;
    if (k < 5)       v = W1[l * 5 + k];
    else if (k == 5) v = b1[l];
    else             v = W2[l * 5 + (k - 6)];
    pw[i] = (f32x2){v, v};
}

__global__ __launch_bounds__(256) void drn_kernel(
    const float* __restrict__ x1, const float* __restrict__ x2,
    const f32x2* __restrict__ pw,
    float* __restrict__ o1, float* __restrict__ o2, int nrows)
{
    long t = (long)blockIdx.x * blockDim.x + threadIdx.x;
    long row0 = t * 8;                 // 8 rows per thread
    if (row0 >= nrows) return;

    // Loads: x1 -> 2 float4; x2 -> 40 floats = 10 float4 (160B/thread, aligned).
    float h1s[8];
    const float4* px1 = (const float4*)(x1 + row0);
    *(float4*)&h1s[0] = px1[0];
    *(float4*)&h1s[4] = px1[1];
    float xs[40];
    const float4* px2 = (const float4*)(x2 + row0 * 5);
    #pragma unroll
    for (int i = 0; i < 10; ++i) ((float4*)xs)[i] = px2[i];

    // Pack row-pairs: pair p = rows (2p, 2p+1). Pure SSA renaming.
    f32x2 h1p[4];
    f32x2 h2[5][4];
    #pragma unroll
    for (int p = 0; p < 4; ++p) {
        h1p[p] = (f32x2){h1s[2 * p], h1s[2 * p + 1]};
        #pragma unroll
        for (int j = 0; j < 5; ++j)
            h2[j][p] = (f32x2){xs[(2 * p) * 5 + j], xs[(2 * p + 1) * 5 + j]};
    }

    const f32x2 zero = (f32x2){0.0f, 0.0f};

    #pragma unroll
    for (int l = 0; l < NL; ++l) {
        // Uniform address, read-only, no aliasing stores -> s_load_dwordx2.
        const f32x2* P = pw + l * 11;
        f32x2 w1d[5], w2d[5];
        #pragma unroll
        for (int j = 0; j < 5; ++j) w1d[j] = P[j];
        f32x2 bd = P[5];
        #pragma unroll
        for (int j = 0; j < 5; ++j) w2d[j] = P[6 + j];

        #pragma unroll
        for (int p = 0; p < 4; ++p) {
            f32x2 s = h1p[p] + bd;
            #pragma unroll
            for (int j = 0; j < 5; ++j)
                s = __builtin_elementwise_fma(
                        __builtin_elementwise_max(h2[j][p], zero), w1d[j], s);
            h1p[p] = s;
            f32x2 rh = __builtin_elementwise_max(s, zero);
            #pragma unroll
            for (int j = 0; j < 5; ++j)
                h2[j][p] = __builtin_elementwise_fma(rh, w2d[j], h2[j][p]);
        }
    }

    // Unpack and store.
    float ys[40];
    #pragma unroll
    for (int p = 0; p < 4; ++p) {
        h1s[2 * p]     = h1p[p].x;
        h1s[2 * p + 1] = h1p[p].y;
        #pragma unroll
        for (int j = 0; j < 5; ++j) {
            ys[(2 * p) * 5 + j]     = h2[j][p].x;
            ys[(2 * p + 1) * 5 + j] = h2[j][p].y;
        }
    }
    float4* po1 = (float4*)(o1 + row0);
    po1[0] = *(float4*)&h1s[0];
    po1[1] = *(float4*)&h1s[4];
    float4* po2 = (float4*)(o2 + row0 * 5);
    #pragma unroll
    for (int i = 0; i < 10; ++i) po2[i] = ((float4*)ys)[i];
}

extern "C" void kernel_launch(void* const* d_in, const int* in_sizes, int n_in,
                              void* d_out, int out_size, void* d_ws, size_t ws_size,
                              hipStream_t stream) {
    const float* x1 = (const float*)d_in[0];
    const float* x2 = (const float*)d_in[1];
    const float* W1 = (const float*)d_in[2];
    const float* b1 = (const float*)d_in[3];
    const float* W2 = (const float*)d_in[4];
    int nrows = in_sizes[0];            // 4,194,304
    float* o1 = (float*)d_out;          // [nrows]
    float* o2 = (float*)d_out + nrows;  // [nrows*5]
    f32x2* pw = (f32x2*)d_ws;           // 30*11*8 = 2640 B of scratch

    pack_params<<<2, 256, 0, stream>>>(W1, b1, W2, pw);

    int nthreads = nrows / 8;           // 8 rows per thread
    int block = 256;
    int grid = (nthreads + block - 1) / block;   // 2048 blocks
    drn_kernel<<<grid, block, 0, stream>>>(x1, x2, pw, o1, o2, nrows);
}